// Round 12
// baseline (264.120 us; speedup 1.0000x reference)
//
#include <hip/hip_runtime.h>
#include <stdint.h>

#define NUM_ENTRIES 1000000
#define NUM_HINTS   32768
#define MAX_SUBSET  512
#define CHUNKS      5

typedef unsigned u32x4a4  __attribute__((ext_vector_type(4), aligned(4)));
typedef unsigned u32x4a16 __attribute__((ext_vector_type(4), aligned(16)));

// Round-5/11 structure + FORCED gather MLP:
//   - sched_barrier(0) between the 16 gather loads and their XOR consumption
//     prevents the compiler from sinking consumes between loads (R11 showed
//     VGPR=24 -> it had serialized the burst away). All 16 loads now issue
//     back-to-back; ~40 result VGPRs live across the barrier.
//   - launch_bounds(256,4): 128-VGPR cap (was 64) so the burst fits, still
//     16 waves/CU -> 256 outstanding gathers/CU (~3x round 5).
__global__ __launch_bounds__(256, 4) void hint_xor_kernel(
    const void* __restrict__ entries_v,
    const void* __restrict__ indices_v,
    const void* __restrict__ mask_v,
    int* __restrict__ out)
{
    const int wave = threadIdx.x >> 6;
    const int lane = threadIdx.x & 63;
    const int hint = blockIdx.x * 4 + wave;

    // ---- layout detection (wave-uniform votes, FP <= 2^-64) ----
    const unsigned* ew = (const unsigned*)entries_v;
    const unsigned* iw = (const unsigned*)indices_v;
    const unsigned* mw = (const unsigned*)mask_v;
    const unsigned es = ew[lane];
    const unsigned is = iw[lane];
    const unsigned ms = mw[lane];
    const bool odd = (lane & 1) != 0;
    const bool ent32   = __any(odd && (es & 0xC0000000u));
    const bool idx32   = __any(odd && (is != 0u));
    const bool m_bytes = __any((ms != 0u) && (ms != 1u) && (ms != 0x3f800000u));
    const bool m_odd_nz = __any(odd && (ms != 0u));
    const int  mstep = m_odd_nz ? 1 : 2;

    unsigned acc0 = 0, acc1 = 0, acc2 = 0, acc3 = 0, acc4 = 0;

    if (ent32 && idx32 && m_bytes) {
        // ================= fast path (confirmed layouts) =================
        const int*      idxp = (const int*)indices_v;
        const unsigned* mwp  = (const unsigned*)mask_v;
        const char*     ebase = (const char*)entries_v;
        const size_t    hbase = (size_t)hint * MAX_SUBSET;

        // Lane owns slots {4l..4l+3} u {256+4l..256+4l+3}; stream loads are
        // contiguous per wave -> each line fetched once (NT: no L2 pollution).
        const u32x4a16 i0 = __builtin_nontemporal_load((const u32x4a16*)(idxp + hbase) + lane);
        const u32x4a16 i1 = __builtin_nontemporal_load((const u32x4a16*)(idxp + hbase + 256) + lane);
        const unsigned m0 = __builtin_nontemporal_load(mwp + (hbase >> 2) + lane);
        const unsigned m1 = __builtin_nontemporal_load(mwp + (hbase >> 2) + 64 + lane);

        unsigned off[8], xm[8];
        #pragma unroll
        for (int c = 0; c < 4; ++c) {
            const unsigned b0 = (m0 >> (8 * c)) & 0xFFu;
            const unsigned b1 = (m1 >> (8 * c)) & 0xFFu;
            const unsigned v0 = (unsigned)i0[c];
            const unsigned v1 = (unsigned)i1[c];
            const bool ok0 = b0 && (v0 < (unsigned)NUM_ENTRIES);  // bounds guard
            const bool ok1 = b1 && (v1 < (unsigned)NUM_ENTRIES);
            off[c]     = ok0 ? v0 * 20u : 0u;        // invalid -> row 0 (L1-hot)
            xm[c]      = ok0 ? 0xFFFFFFFFu : 0u;
            off[4 + c] = ok1 ? v1 * 20u : 0u;
            xm[4 + c]  = ok1 ? 0xFFFFFFFFu : 0u;
        }

        // 16 independent gather loads, issued back-to-back.
        u32x4a4 q[8]; unsigned w[8];
        #pragma unroll
        for (int t = 0; t < 8; ++t) {
            q[t] = *(const u32x4a4*)(ebase + off[t]);
            w[t] = *(const unsigned*)(ebase + off[t] + 16);
        }
        // Hard scheduling fence: no consume may be hoisted above this point,
        // so all 16 loads are in flight before the first s_waitcnt.
        __builtin_amdgcn_sched_barrier(0);
        #pragma unroll
        for (int t = 0; t < 8; ++t) {
            acc0 ^= q[t].x & xm[t];
            acc1 ^= q[t].y & xm[t];
            acc2 ^= q[t].z & xm[t];
            acc3 ^= q[t].w & xm[t];
            acc4 ^= w[t]   & xm[t];
        }
    } else {
        // ================= generic fallback (any layout) =================
        const int*           idx32p = (const int*)indices_v;
        const long long*     idx64p = (const long long*)indices_v;
        const unsigned char* m8p    = (const unsigned char*)mask_v;
        const unsigned*      m32p   = (const unsigned*)mask_v;

        const size_t rowoff = (size_t)hint * MAX_SUBSET;
        #pragma unroll 1
        for (int k = 0; k < 8; ++k) {
            const size_t s = rowoff + (size_t)(k * 64 + lane);
            long long idx = idx32 ? (long long)idx32p[s] : idx64p[s];
            unsigned mv = m_bytes ? (unsigned)m8p[s] : m32p[s * (size_t)mstep];
            const bool v = (mv != 0u) &&
                           ((unsigned long long)idx < (unsigned long long)NUM_ENTRIES);
            if (v) {
                if (ent32) {
                    const unsigned* e = (const unsigned*)entries_v + (size_t)idx * 5u;
                    acc0 ^= e[0]; acc1 ^= e[1]; acc2 ^= e[2]; acc3 ^= e[3]; acc4 ^= e[4];
                } else {
                    const unsigned* e = (const unsigned*)entries_v + (size_t)idx * 10u;
                    acc0 ^= e[0]; acc1 ^= e[2]; acc2 ^= e[4]; acc3 ^= e[6]; acc4 ^= e[8];
                }
            }
        }
    }

    // 64-lane XOR butterfly
    #pragma unroll
    for (int o = 32; o >= 1; o >>= 1) {
        acc0 ^= (unsigned)__shfl_xor((int)acc0, o, 64);
        acc1 ^= (unsigned)__shfl_xor((int)acc1, o, 64);
        acc2 ^= (unsigned)__shfl_xor((int)acc2, o, 64);
        acc3 ^= (unsigned)__shfl_xor((int)acc3, o, 64);
        acc4 ^= (unsigned)__shfl_xor((int)acc4, o, 64);
    }

    // coalesced epilogue: lanes 0..4 write one dword each
    if (lane < CHUNKS) {
        unsigned r = acc0;
        r = (lane == 1) ? acc1 : r;
        r = (lane == 2) ? acc2 : r;
        r = (lane == 3) ? acc3 : r;
        r = (lane == 4) ? acc4 : r;
        out[(size_t)hint * CHUNKS + lane] = (int)r;
    }
}

extern "C" void kernel_launch(void* const* d_in, const int* in_sizes, int n_in,
                              void* d_out, int out_size, void* d_ws, size_t ws_size,
                              hipStream_t stream) {
    const void* entries = d_in[0];
    const void* indices = d_in[1];
    const void* mask    = d_in[2];
    int*        out     = (int*)d_out;

    // 4 waves/block, one wave per hint -> 8192 blocks
    hint_xor_kernel<<<NUM_HINTS / 4, 256, 0, stream>>>(entries, indices, mask, out);
}